// Round 1
// baseline (326.967 us; speedup 1.0000x reference)
//
#include <hip/hip_runtime.h>

// Space-to-depth (pixel "unshuffle"), s=2.
// in : (B=4, C=3, T=16, H=512, W=512) fp32
// out: (B, C*4, T, H/2, W/2) fp32
// out[b, sh*2C + sw*C + c, t, hc, wc] = in[b, c, t, 2*hc+sh, 2*wc+sw]

constexpr int B  = 4;
constexpr int C  = 3;
constexpr int T  = 16;
constexpr int H  = 512;
constexpr int W  = 512;
constexpr int S  = 2;
constexpr int Hc = H / S;   // 256
constexpr int Wc = W / S;   // 256
constexpr int K  = C * S * S; // 12

// Each thread handles 8 consecutive floats along W of one input row:
// two float4 loads -> two float4 stores (one per sw row).
constexpr int WCHUNK   = 8;
constexpr int W8       = W / WCHUNK;                // 64 chunks per row
constexpr long NTHREAD = (long)B * C * T * H * W8;  // 6,291,456
constexpr int  BLOCK   = 256;

__global__ __launch_bounds__(BLOCK) void s2d_kernel(const float* __restrict__ in,
                                                    float* __restrict__ out) {
    int id = blockIdx.x * BLOCK + threadIdx.x;

    // id layout (fastest->slowest): w8 (64) | h (512) | t (16) | c (3) | b (4)
    int w8 = id & (W8 - 1);
    int h  = (id >> 6) & (H - 1);
    int t  = (id >> 15) & (T - 1);
    int ct = id >> 19;            // 0..11
    int c  = ct % C;
    int b  = ct / C;

    int hc = h >> 1;
    int sh = h & 1;

    const float4* src = reinterpret_cast<const float4*>(
        in + ((((long)(b * C + c) * T + t) * H + h) * W) + (long)w8 * WCHUNK);
    float4 v0 = src[0];
    float4 v1 = src[1];

    int  wc0 = w8 * 4;
    int  k0  = sh * (S * C) + c;               // sw = 0 plane
    long obase = (((long)(b * K + k0) * T + t) * Hc + hc) * (long)Wc + wc0;

    float4 o0 = make_float4(v0.x, v0.z, v1.x, v1.z);  // sw = 0 elements
    float4 o1 = make_float4(v0.y, v0.w, v1.y, v1.w);  // sw = 1 elements

    *reinterpret_cast<float4*>(out + obase) = o0;
    // k1 = k0 + C  -> offset by C * T * Hc * Wc
    *reinterpret_cast<float4*>(out + obase + (long)C * T * Hc * Wc) = o1;
}

extern "C" void kernel_launch(void* const* d_in, const int* in_sizes, int n_in,
                              void* d_out, int out_size, void* d_ws, size_t ws_size,
                              hipStream_t stream) {
    const float* in = (const float*)d_in[0];
    float* out      = (float*)d_out;

    int grid = (int)(NTHREAD / BLOCK);  // 24576
    s2d_kernel<<<grid, BLOCK, 0, stream>>>(in, out);
}

// Round 3
// 317.438 us; speedup vs baseline: 1.0300x; 1.0300x over previous
//
#include <hip/hip_runtime.h>

// Space-to-depth (pixel "unshuffle"), s=2.
// in : (B=4, C=3, T=16, H=512, W=512) fp32
// out: (B, C*4, T, H/2, W/2) fp32
// out[b, sh*2C + sw*C + c, t, hc, wc] = in[b, c, t, 2*hc+sh, 2*wc+sw]
//
// One thread handles BOTH rows (sh=0,1) of one hc and 8 consecutive floats
// along W: 4x vec4 nontemporal loads -> 4x vec4 nontemporal stores, one per
// (sh,sw) plane. Plane offsets from the k=c base are compile-time constants:
// k = sh*6 + sw*3 + c -> 0, 3P, 6P, 9P.
//
// NOTE: __builtin_nontemporal_* requires a clang vector type, not HIP's
// float4 class — use ext_vector_type(4).

typedef float v4f __attribute__((ext_vector_type(4)));

constexpr int  B  = 4;
constexpr int  C  = 3;
constexpr int  T  = 16;
constexpr int  H  = 512;
constexpr int  W  = 512;
constexpr int  Hc = H / 2;          // 256
constexpr int  Wc = W / 2;          // 256
constexpr int  K  = C * 4;          // 12
constexpr long PLANE = (long)T * Hc * Wc;  // per-k stride in output

constexpr int  WCHUNK  = 8;
constexpr int  W8      = W / WCHUNK;                  // 64 chunks per row
constexpr long NTHREAD = (long)B * C * T * Hc * W8;   // 3,145,728
constexpr int  BLOCK   = 256;

__global__ __launch_bounds__(BLOCK) void s2d_kernel(const float* __restrict__ in,
                                                    float* __restrict__ out) {
    int id = blockIdx.x * BLOCK + threadIdx.x;

    // id layout (fastest->slowest): w8 (64) | hc (256) | t (16) | c (3) | b (4)
    int w8 = id & (W8 - 1);
    int hc = (id >> 6) & (Hc - 1);
    int t  = (id >> 14) & (T - 1);
    int ct = id >> 18;            // 0..11
    int c  = ct % C;
    int b  = ct / C;

    const v4f* row0 = reinterpret_cast<const v4f*>(
        in + ((((long)(b * C + c) * T + t) * H + 2 * hc) * W) + (long)w8 * WCHUNK);
    const v4f* row1 = row0 + (W / 4);

    v4f r00 = __builtin_nontemporal_load(row0 + 0);
    v4f r01 = __builtin_nontemporal_load(row0 + 1);
    v4f r10 = __builtin_nontemporal_load(row1 + 0);
    v4f r11 = __builtin_nontemporal_load(row1 + 1);

    long obase = (((long)(b * K + c) * T + t) * Hc + hc) * (long)Wc + (long)w8 * 4;

    v4f o00 = {r00.x, r00.z, r01.x, r01.z};  // sh=0, sw=0
    v4f o01 = {r00.y, r00.w, r01.y, r01.w};  // sh=0, sw=1
    v4f o10 = {r10.x, r10.z, r11.x, r11.z};  // sh=1, sw=0
    v4f o11 = {r10.y, r10.w, r11.y, r11.w};  // sh=1, sw=1

    __builtin_nontemporal_store(o00, reinterpret_cast<v4f*>(out + obase));
    __builtin_nontemporal_store(o01, reinterpret_cast<v4f*>(out + obase + 3 * PLANE));
    __builtin_nontemporal_store(o10, reinterpret_cast<v4f*>(out + obase + 6 * PLANE));
    __builtin_nontemporal_store(o11, reinterpret_cast<v4f*>(out + obase + 9 * PLANE));
}

extern "C" void kernel_launch(void* const* d_in, const int* in_sizes, int n_in,
                              void* d_out, int out_size, void* d_ws, size_t ws_size,
                              hipStream_t stream) {
    const float* in = (const float*)d_in[0];
    float* out      = (float*)d_out;

    int grid = (int)(NTHREAD / BLOCK);  // 12288
    s2d_kernel<<<grid, BLOCK, 0, stream>>>(in, out);
}